// Round 3
// baseline (44572.681 us; speedup 1.0000x reference)
//
#include <hip/hip_runtime.h>

// ---------------------------------------------------------------------------
// NS_Flashed_TotalSimRetina — GLM retina simulation, round 3.
// Scatter-form recurrence: thread (b,c) holds acc[100] f32 in VGPRs = future
// gensig contributions of its cell. Per step it gathers 21 source spikes
// (cheap) and scatters them over 100 future slots (register-resident, edge-
// paired v_dot2_f32_f16). wg = 16 cells x 32 batches so weights are shared
// across batch lanes (kills the per-CU L2 weight-stream wall of the gather
// form). Cross-wg spike exchange: linear global ring, data-as-flag polling
// (poison 0xAAAAAAAA), agent-scope atomics, no barriers, no LDS.
// ---------------------------------------------------------------------------

#define NC     600
#define NPIX   4096
#define NBF    100
#define MC     20
#define NB     500
#define NBI    100
#define NBATCH 32
#define NSTEP  400
#define CPW    16                      // cells per workgroup
#define NWG    ((NC + CPW - 1) / CPW)  // 38
#define POISON 0xAAAAAAAAu

typedef unsigned int u32;
typedef _Float16 f16x2 __attribute__((ext_vector_type(2)));

__device__ __forceinline__ float dot2(u32 a, u32 b, float acc) {
  return __builtin_amdgcn_fdot2(__builtin_bit_cast(f16x2, a),
                                __builtin_bit_cast(f16x2, b), acc, false);
}
__device__ __forceinline__ u32 pkrtz(float a, float b) {
  return __builtin_bit_cast(u32, __builtin_amdgcn_cvt_pkrtz(a, b));
}
__device__ __forceinline__ u32 aload(const u32* p) {
  return __hip_atomic_load(p, __ATOMIC_RELAXED, __HIP_MEMORY_SCOPE_AGENT);
}
__device__ __forceinline__ void astore(u32* p, u32 v) {
  __hip_atomic_store(p, v, __ATOMIC_RELAXED, __HIP_MEMORY_SCOPE_AGENT);
}

// --- poison the spike ring (don't rely on harness 0xAA fill) ---------------
__global__ void clear_kernel(u32* __restrict__ p, int n) {
  int i = blockIdx.x * 256 + threadIdx.x;
  if (i < n) p[i] = POISON;
}

// --- stim_applied[b][c] = sum_p stim[b][p] * spat[c][p] ---------------------
__global__ void applied_kernel(const float* __restrict__ stim,
                               const float* __restrict__ spat,
                               float* __restrict__ applied) {
  const int c = blockIdx.x, b = blockIdx.y;
  __shared__ float red[256];
  float a = 0.f;
  for (int p = threadIdx.x; p < NPIX; p += 256)
    a += stim[b * NPIX + p] * spat[c * NPIX + p];
  red[threadIdx.x] = a;
  __syncthreads();
  for (int s = 128; s > 0; s >>= 1) {
    if (threadIdx.x < s) red[threadIdx.x] += red[threadIdx.x + s];
    __syncthreads();
  }
  if (threadIdx.x == 0) applied[b * NC + c] = red[0];
}

// --- convT[t][c] = sum_f stc[t+f] * tcf[c][f] ------------------------------
__global__ void conv_kernel(const float* __restrict__ stc,
                            const float* __restrict__ tcf,
                            float* __restrict__ convT) {
  int idx = blockIdx.x * 256 + threadIdx.x;
  if (idx >= NSTEP * NC) return;
  int t = idx / NC, c = idx - t * NC;
  float a = 0.f;
  for (int f = 0; f < NBF; ++f)
    a += stc[t + f] * tcf[c * NBF + f];
  convT[idx] = a;
}

// --- packed, time-reversed, edge-paired filter table -----------------------
// wrevP[c][p][i] (dword, f16x2): pair p<10 -> (cf[c][2p][99-i], cf[c][2p+1][99-i]);
// p==10 -> (ff[c][99-i], 0). 600*11*100 dwords, 16B-aligned rows for uint4.
__global__ void pack_kernel(const float* __restrict__ cf,
                            const float* __restrict__ ff,
                            u32* __restrict__ wrevP) {
  int idx = blockIdx.x * 256 + threadIdx.x;
  if (idx >= NC * 1100) return;
  int c = idx / 1100;
  int r = idx - c * 1100;
  int p = r / 100;
  int i = r - p * 100;
  int f = 99 - i;
  float lo, hi;
  if (p < 10) {
    lo = cf[(c * MC + 2 * p) * NBF + f];
    hi = cf[(c * MC + 2 * p + 1) * NBF + f];
  } else {
    lo = ff[c * NBF + f];
    hi = 0.f;
  }
  wrevP[idx] = pkrtz(lo, hi);
}

// --- packed source pairs selP[c][p] = src0 | (src1 << 16), p < 10 ----------
__global__ void selp_kernel(const int* __restrict__ sel, u32* __restrict__ selP) {
  int idx = blockIdx.x * 256 + threadIdx.x;
  if (idx >= NC * 10) return;
  int c = idx / 10, p = idx - c * 10;
  u32 s0 = (u32)sel[c * MC + 2 * p];
  u32 s1 = (u32)sel[c * MC + 2 * p + 1];
  selP[idx] = s0 | (s1 << 16);
}

// --- copy initial spikes into output (first 100 bins of each row) ----------
__global__ void copy_init_kernel(const float4* __restrict__ init,
                                 float4* __restrict__ out) {
  int idx = blockIdx.x * 256 + threadIdx.x;
  if (idx >= NBATCH * NC * (NBI / 4)) return;
  int k4 = idx % (NBI / 4);
  int bc = idx / (NBI / 4);
  out[bc * (NB / 4) + k4] = init[idx];
}

// --- the recurrence --------------------------------------------------------
__global__ __launch_bounds__(512) void sim_kernel(
    const float* __restrict__ init, const float* __restrict__ bias,
    const float* __restrict__ applied, const float* __restrict__ convT,
    const u32* __restrict__ wrevP, const u32* __restrict__ selP,
    u32* __restrict__ ring, float* __restrict__ out) {
  const int tid = threadIdx.x;
  const int b = tid & 31;
  const int ch = tid >> 5;
  const int c = blockIdx.x * CPW + ch;
  if (c >= NC) return;  // no barriers in this kernel -> early exit is safe

  float acc[NBF];
#pragma unroll
  for (int i = 0; i < NBF; ++i) acc[i] = 0.f;

  u32 selp[10];
#pragma unroll
  for (int p = 0; p < 10; ++p) selp[p] = selP[c * 10 + p];

  const float biasv = bias[c];
  const float appv  = applied[b * NC + c];
  const float* initB = init + (size_t)b * (NC * NBI);  // [src][k]
  const u32* wb = wrevP + c * 1100;
  float* outS = out + (size_t)(b * NC + c) * NB + NBI;
  float* outG = out + (size_t)NBATCH * NC * NB + (size_t)(b * NC + c) * NSTEP;

#pragma unroll 1
  for (int t = -NBI; t < NSTEP; ++t) {
    float sv;
    u32 u0[10], u1[10];
    if (t >= 0) {
      float g = biasv + appv * convT[t * NC + c] + acc[0];
      sv = 1.f / (1.f + __expf(-g));
      outS[t] = sv;
      outG[t] = g;
      // publish own spike FIRST (consumers at step t poll it), then gather
      u32* rt_w = ring + (size_t)t * (NC * NBATCH) + b;
      astore(rt_w + c * NBATCH, __builtin_bit_cast(u32, sv));
      const u32* rt = rt_w;
#pragma unroll
      for (int p = 0; p < 10; ++p) {
        u0[p] = aload(rt + (selp[p] & 0xffffu) * NBATCH);
        u1[p] = aload(rt + (selp[p] >> 16) * NBATCH);
      }
      // straggler polling (spike f32 in (0,1) can never equal POISON)
      while (true) {
        bool any = false;
#pragma unroll
        for (int p = 0; p < 10; ++p) {
          if (u0[p] == POISON) {
            u0[p] = aload(rt + (selp[p] & 0xffffu) * NBATCH);
            any = any || (u0[p] == POISON);
          }
          if (u1[p] == POISON) {
            u1[p] = aload(rt + (selp[p] >> 16) * NBATCH);
            any = any || (u1[p] == POISON);
          }
        }
        if (!any) break;
        __builtin_amdgcn_s_sleep(2);
      }
    } else {
      const int k = t + NBI;  // absolute time 0..99 -> initial spikes
      sv = initB[c * NBI + k];
#pragma unroll
      for (int p = 0; p < 10; ++p) {
        u0[p] = __builtin_bit_cast(u32, initB[(selp[p] & 0xffffu) * NBI + k]);
        u1[p] = __builtin_bit_cast(u32, initB[(selp[p] >> 16) * NBI + k]);
      }
    }

    u32 sp[11];
#pragma unroll
    for (int p = 0; p < 10; ++p)
      sp[p] = pkrtz(__builtin_bit_cast(float, u0[p]),
                    __builtin_bit_cast(float, u1[p]));
    sp[10] = pkrtz(sv, 0.f);  // feedback edge: own spike, zero partner

    // rotate: acc[i] <- contributions to step (t+1)+i
#pragma unroll
    for (int i = 0; i < NBF - 1; ++i) acc[i] = acc[i + 1];
    acc[NBF - 1] = 0.f;

    // scatter: acc[i] += wrev[i] . sp  (2 edges per dot2)
#pragma unroll
    for (int p = 0; p < 11; ++p) {
#pragma unroll
      for (int ib = 0; ib < 25; ++ib) {
        const uint4 w = *(const uint4*)(wb + p * 100 + ib * 4);
        acc[ib * 4 + 0] = dot2(w.x, sp[p], acc[ib * 4 + 0]);
        acc[ib * 4 + 1] = dot2(w.y, sp[p], acc[ib * 4 + 1]);
        acc[ib * 4 + 2] = dot2(w.z, sp[p], acc[ib * 4 + 2]);
        acc[ib * 4 + 3] = dot2(w.w, sp[p], acc[ib * 4 + 3]);
      }
    }
  }
}

extern "C" void kernel_launch(void* const* d_in, const int* in_sizes, int n_in,
                              void* d_out, int out_size, void* d_ws, size_t ws_size,
                              hipStream_t stream) {
  const float* stim = (const float*)d_in[0];   // 32x64x64
  const float* init = (const float*)d_in[1];   // 32x600x100
  const float* spat = (const float*)d_in[2];   // 600x4096
  const float* tcf  = (const float*)d_in[3];   // 600x100
  const float* ff   = (const float*)d_in[4];   // 600x100
  const float* cf   = (const float*)d_in[5];   // 600x20x100
  const float* bias = (const float*)d_in[6];   // 600x1
  const int*   sel  = (const int*)d_in[7];     // 600x20 int32
  const float* stc  = (const float*)d_in[8];   // 500
  float* out = (float*)d_out;                  // spikes 32x600x500, gensig 32x600x400

  char* ws = (char*)d_ws;
  float* applied = (float*)ws;                         //     76,800 B
  float* convT   = (float*)(ws + 76800);               //    960,000 B
  u32*   wrevP   = (u32*)(ws + 1036800);               //  2,640,000 B
  u32*   selP    = (u32*)(ws + 3676800);               //     24,000 B
  u32*   ring    = (u32*)(ws + 3700800);               // 30,720,000 B (400x600x32 f32)
  (void)ws_size; (void)in_sizes; (void)n_in; (void)out_size;

  const int ringN = NSTEP * NC * NBATCH;  // 7,680,000 dwords
  hipLaunchKernelGGL(clear_kernel, dim3((ringN + 255) / 256), dim3(256), 0,
                     stream, ring, ringN);
  hipLaunchKernelGGL(applied_kernel, dim3(NC, NBATCH), dim3(256), 0, stream,
                     stim, spat, applied);
  hipLaunchKernelGGL(conv_kernel, dim3((NSTEP * NC + 255) / 256), dim3(256), 0,
                     stream, stc, tcf, convT);
  hipLaunchKernelGGL(pack_kernel, dim3((NC * 1100 + 255) / 256), dim3(256), 0,
                     stream, cf, ff, wrevP);
  hipLaunchKernelGGL(selp_kernel, dim3((NC * 10 + 255) / 256), dim3(256), 0,
                     stream, sel, selP);
  hipLaunchKernelGGL(copy_init_kernel,
                     dim3((NBATCH * NC * (NBI / 4) + 255) / 256), dim3(256), 0,
                     stream, (const float4*)init, (float4*)out);
  hipLaunchKernelGGL(sim_kernel, dim3(NWG), dim3(512), 0, stream,
                     init, bias, applied, convT, wrevP, selP, ring, out);
}

// Round 4
// 13146.014 us; speedup vs baseline: 3.3906x; 3.3906x over previous
//
#include <hip/hip_runtime.h>

// ---------------------------------------------------------------------------
// NS_Flashed_TotalSimRetina — GLM retina simulation, round 4.
// Scatter-form recurrence (round 3) with the communication fixed:
//  - uniform spike ring ring[tau][c][b], tau<100 prefilled from transposed
//    initial spikes (no special init gather path)
//  - per-step counter barrier: one relaxed atomic inc per wg (after
//    __syncthreads, which drains vmcnt for all waves), consumers poll ONE
//    dword then gather each source exactly once (no per-value polling storm)
//  - rotation + feedback scatter run before the poll to hide barrier latency
// 75 wgs x 256 threads = 8 cells x 32 batches each (75*8 = 600).
// ---------------------------------------------------------------------------

#define NC     600
#define NPIX   4096
#define NBF    100
#define MC     20
#define NB     500
#define NBI    100
#define NBATCH 32
#define NSTEP  400
#define CPW    8                       // cells per workgroup
#define NWG    (NC / CPW)              // 75
#define NCB    (NC * NBATCH)           // 19200

typedef unsigned int u32;
typedef _Float16 f16x2 __attribute__((ext_vector_type(2)));

__device__ __forceinline__ float dot2(u32 a, u32 b, float acc) {
  return __builtin_amdgcn_fdot2(__builtin_bit_cast(f16x2, a),
                                __builtin_bit_cast(f16x2, b), acc, false);
}
__device__ __forceinline__ u32 pkrtz(float a, float b) {
  return __builtin_bit_cast(u32, __builtin_amdgcn_cvt_pkrtz(a, b));
}
__device__ __forceinline__ u32 aload(const u32* p) {
  return __hip_atomic_load(p, __ATOMIC_RELAXED, __HIP_MEMORY_SCOPE_AGENT);
}
__device__ __forceinline__ void astore(u32* p, u32 v) {
  __hip_atomic_store(p, v, __ATOMIC_RELAXED, __HIP_MEMORY_SCOPE_AGENT);
}
__device__ __forceinline__ void ainc(u32* p) {
  __hip_atomic_fetch_add(p, 1u, __ATOMIC_RELAXED, __HIP_MEMORY_SCOPE_AGENT);
}

// --- zero the per-step counters --------------------------------------------
__global__ void clear_kernel(u32* __restrict__ cnt) {
  int i = blockIdx.x * 256 + threadIdx.x;
  if (i < NSTEP) cnt[i] = 0u;
}

// --- stim_applied[b][c] = sum_p stim[b][p] * spat[c][p] ---------------------
__global__ void applied_kernel(const float* __restrict__ stim,
                               const float* __restrict__ spat,
                               float* __restrict__ applied) {
  const int c = blockIdx.x, b = blockIdx.y;
  __shared__ float red[256];
  float a = 0.f;
  for (int p = threadIdx.x; p < NPIX; p += 256)
    a += stim[b * NPIX + p] * spat[c * NPIX + p];
  red[threadIdx.x] = a;
  __syncthreads();
  for (int s = 128; s > 0; s >>= 1) {
    if (threadIdx.x < s) red[threadIdx.x] += red[threadIdx.x + s];
    __syncthreads();
  }
  if (threadIdx.x == 0) applied[b * NC + c] = red[0];
}

// --- convT[t][c] = sum_f stc[t+f] * tcf[c][f] ------------------------------
__global__ void conv_kernel(const float* __restrict__ stc,
                            const float* __restrict__ tcf,
                            float* __restrict__ convT) {
  int idx = blockIdx.x * 256 + threadIdx.x;
  if (idx >= NSTEP * NC) return;
  int t = idx / NC, c = idx - t * NC;
  float a = 0.f;
  for (int f = 0; f < NBF; ++f)
    a += stc[t + f] * tcf[c * NBF + f];
  convT[idx] = a;
}

// --- packed, time-reversed, edge-paired filter table -----------------------
// wrevP[c][p][i]: pair p<10 -> (cf[c][2p][99-i], cf[c][2p+1][99-i]);
// p==10 -> (ff[c][99-i], 0).
__global__ void pack_kernel(const float* __restrict__ cf,
                            const float* __restrict__ ff,
                            u32* __restrict__ wrevP) {
  int idx = blockIdx.x * 256 + threadIdx.x;
  if (idx >= NC * 1100) return;
  int c = idx / 1100;
  int r = idx - c * 1100;
  int p = r / 100;
  int i = r - p * 100;
  int f = 99 - i;
  float lo, hi;
  if (p < 10) {
    lo = cf[(c * MC + 2 * p) * NBF + f];
    hi = cf[(c * MC + 2 * p + 1) * NBF + f];
  } else {
    lo = ff[c * NBF + f];
    hi = 0.f;
  }
  wrevP[idx] = pkrtz(lo, hi);
}

// --- packed source pairs selP[c][p] = src0 | (src1 << 16) ------------------
__global__ void selp_kernel(const int* __restrict__ sel, u32* __restrict__ selP) {
  int idx = blockIdx.x * 256 + threadIdx.x;
  if (idx >= NC * 10) return;
  int c = idx / 10, p = idx - c * 10;
  u32 s0 = (u32)sel[c * MC + 2 * p];
  u32 s1 = (u32)sel[c * MC + 2 * p + 1];
  selP[idx] = s0 | (s1 << 16);
}

// --- prefill ring[tau][c][b] = init[b][c][tau] for tau < 100 ---------------
__global__ void initT_kernel(const float* __restrict__ init,
                             float* __restrict__ ring) {
  int idx = blockIdx.x * 256 + threadIdx.x;
  if (idx >= NBI * NCB) return;
  int b = idx & (NBATCH - 1);
  int r = idx >> 5;          // c + NC*tau
  int c = r % NC;
  int tau = r / NC;
  ring[idx] = init[(b * NC + c) * NBI + tau];
}

// --- copy initial spikes into output (first 100 bins of each row) ----------
__global__ void copy_init_kernel(const float4* __restrict__ init,
                                 float4* __restrict__ out) {
  int idx = blockIdx.x * 256 + threadIdx.x;
  if (idx >= NBATCH * NC * (NBI / 4)) return;
  int k4 = idx % (NBI / 4);
  int bc = idx / (NBI / 4);
  out[bc * (NB / 4) + k4] = init[idx];
}

// --- the recurrence --------------------------------------------------------
__global__ __launch_bounds__(256) void sim_kernel(
    const float* __restrict__ bias, const float* __restrict__ applied,
    const float* __restrict__ convT, const u32* __restrict__ wrevP,
    const u32* __restrict__ selP, u32* __restrict__ ring,
    u32* __restrict__ cnt, float* __restrict__ out) {
  const int tid = threadIdx.x;
  const int b = tid & 31;
  const int ch = tid >> 5;
  const int c = blockIdx.x * CPW + ch;

  float acc[NBF];
#pragma unroll
  for (int i = 0; i < NBF; ++i) acc[i] = 0.f;

  u32 selp[10];
#pragma unroll
  for (int p = 0; p < 10; ++p) selp[p] = selP[c * 10 + p];

  const float biasv = bias[c];
  const float appv  = applied[b * NC + c];
  const u32* wb = wrevP + c * 1100;
  float* outS = out + (size_t)(b * NC + c) * NB + NBI;
  float* outG = out + (size_t)NBATCH * NC * NB + (size_t)(b * NC + c) * NSTEP;

#pragma unroll 1
  for (int tau = 0; tau < NB; ++tau) {
    const int t = tau - NBI;
    u32* rt = ring + (size_t)tau * NCB;
    float sv;
    if (t >= 0) {
      float g = biasv + appv * convT[t * NC + c] + acc[0];
      sv = 1.f / (1.f + __expf(-g));
      outS[t] = sv;
      outG[t] = g;
      astore(rt + c * NBATCH + b, __builtin_bit_cast(u32, sv));
      __syncthreads();  // drains vmcnt for ALL waves before the inc below
      if (tid == 0) ainc(&cnt[t]);
    } else {
      sv = __builtin_bit_cast(float, aload(rt + c * NBATCH + b));
    }

    // rotate: acc[i] <- contributions to step (t+1)+i
#pragma unroll
    for (int i = 0; i < NBF - 1; ++i) acc[i] = acc[i + 1];
    acc[NBF - 1] = 0.f;

    // feedback scatter first (local data) — hides barrier latency
    {
      const u32 sp10 = pkrtz(sv, 0.f);
#pragma unroll
      for (int ib = 0; ib < 25; ++ib) {
        const uint4 w = *(const uint4*)(wb + 1000 + ib * 4);
        acc[ib * 4 + 0] = dot2(w.x, sp10, acc[ib * 4 + 0]);
        acc[ib * 4 + 1] = dot2(w.y, sp10, acc[ib * 4 + 1]);
        acc[ib * 4 + 2] = dot2(w.z, sp10, acc[ib * 4 + 2]);
        acc[ib * 4 + 3] = dot2(w.w, sp10, acc[ib * 4 + 3]);
      }
    }

    // wait for all wgs to have published step tau, then gather once
    if (t >= 0) {
      while (aload(&cnt[t]) < NWG) {}
    }
    u32 u0[10], u1[10];
#pragma unroll
    for (int p = 0; p < 10; ++p) {
      u0[p] = aload(rt + (selp[p] & 0xffffu) * NBATCH + b);
      u1[p] = aload(rt + (selp[p] >> 16) * NBATCH + b);
    }
    u32 sp[10];
#pragma unroll
    for (int p = 0; p < 10; ++p)
      sp[p] = pkrtz(__builtin_bit_cast(float, u0[p]),
                    __builtin_bit_cast(float, u1[p]));

    // coupling scatter: acc[i] += wrev[p][i] . sp[p]
#pragma unroll 1
    for (int p = 0; p < 10; ++p) {
#pragma unroll
      for (int ib = 0; ib < 25; ++ib) {
        const uint4 w = *(const uint4*)(wb + p * 100 + ib * 4);
        acc[ib * 4 + 0] = dot2(w.x, sp[p], acc[ib * 4 + 0]);
        acc[ib * 4 + 1] = dot2(w.y, sp[p], acc[ib * 4 + 1]);
        acc[ib * 4 + 2] = dot2(w.z, sp[p], acc[ib * 4 + 2]);
        acc[ib * 4 + 3] = dot2(w.w, sp[p], acc[ib * 4 + 3]);
      }
    }
  }
}

extern "C" void kernel_launch(void* const* d_in, const int* in_sizes, int n_in,
                              void* d_out, int out_size, void* d_ws, size_t ws_size,
                              hipStream_t stream) {
  const float* stim = (const float*)d_in[0];   // 32x64x64
  const float* init = (const float*)d_in[1];   // 32x600x100
  const float* spat = (const float*)d_in[2];   // 600x4096
  const float* tcf  = (const float*)d_in[3];   // 600x100
  const float* ff   = (const float*)d_in[4];   // 600x100
  const float* cf   = (const float*)d_in[5];   // 600x20x100
  const float* bias = (const float*)d_in[6];   // 600x1
  const int*   sel  = (const int*)d_in[7];     // 600x20 int32
  const float* stc  = (const float*)d_in[8];   // 500
  float* out = (float*)d_out;                  // spikes 32x600x500, gensig 32x600x400

  char* ws = (char*)d_ws;
  u32*   ring    = (u32*)ws;                         // 38,400,000 B (500x600x32 f32)
  float* applied = (float*)(ws + 38400000);          //     76,800 B
  float* convT   = (float*)(ws + 38476800);          //    960,000 B
  u32*   wrevP   = (u32*)(ws + 39436800);            //  2,640,000 B
  u32*   selP    = (u32*)(ws + 42076800);            //     24,000 B
  u32*   cnt     = (u32*)(ws + 42100800);            //      1,600 B  (end ~42.1 MB)
  (void)ws_size; (void)in_sizes; (void)n_in; (void)out_size;

  hipLaunchKernelGGL(clear_kernel, dim3((NSTEP + 255) / 256), dim3(256), 0,
                     stream, cnt);
  hipLaunchKernelGGL(applied_kernel, dim3(NC, NBATCH), dim3(256), 0, stream,
                     stim, spat, applied);
  hipLaunchKernelGGL(conv_kernel, dim3((NSTEP * NC + 255) / 256), dim3(256), 0,
                     stream, stc, tcf, convT);
  hipLaunchKernelGGL(pack_kernel, dim3((NC * 1100 + 255) / 256), dim3(256), 0,
                     stream, cf, ff, wrevP);
  hipLaunchKernelGGL(selp_kernel, dim3((NC * 10 + 255) / 256), dim3(256), 0,
                     stream, sel, selP);
  hipLaunchKernelGGL(initT_kernel, dim3((NBI * NCB + 255) / 256), dim3(256), 0,
                     stream, init, (float*)ring);
  hipLaunchKernelGGL(copy_init_kernel,
                     dim3((NBATCH * NC * (NBI / 4) + 255) / 256), dim3(256), 0,
                     stream, (const float4*)init, (float4*)out);
  hipLaunchKernelGGL(sim_kernel, dim3(NWG), dim3(256), 0, stream,
                     bias, applied, convT, wrevP, selP, ring, cnt, out);
}

// Round 5
// 12940.775 us; speedup vs baseline: 3.4444x; 1.0159x over previous
//
#include <hip/hip_runtime.h>

// ---------------------------------------------------------------------------
// NS_Flashed_TotalSimRetina — GLM retina simulation, round 5.
// Identical scatter-form algorithm to round 4; only the per-step barrier is
// restructured to kill MALL same-line contention:
//   - only wave 0 of each wg polls cnt[t] (75 pollers, was 300), with
//     s_sleep backoff; other waves wait at a second __syncthreads
//   - rotate + feedback scatter moved between the inc and the poll to hide
//     barrier latency under local compute
// 75 wgs x 256 threads = 8 cells x 32 batches each.
// ---------------------------------------------------------------------------

#define NC     600
#define NPIX   4096
#define NBF    100
#define MC     20
#define NB     500
#define NBI    100
#define NBATCH 32
#define NSTEP  400
#define CPW    8                       // cells per workgroup
#define NWG    (NC / CPW)              // 75
#define NCB    (NC * NBATCH)           // 19200

typedef unsigned int u32;
typedef _Float16 f16x2 __attribute__((ext_vector_type(2)));

__device__ __forceinline__ float dot2(u32 a, u32 b, float acc) {
  return __builtin_amdgcn_fdot2(__builtin_bit_cast(f16x2, a),
                                __builtin_bit_cast(f16x2, b), acc, false);
}
__device__ __forceinline__ u32 pkrtz(float a, float b) {
  return __builtin_bit_cast(u32, __builtin_amdgcn_cvt_pkrtz(a, b));
}
__device__ __forceinline__ u32 aload(const u32* p) {
  return __hip_atomic_load(p, __ATOMIC_RELAXED, __HIP_MEMORY_SCOPE_AGENT);
}
__device__ __forceinline__ void astore(u32* p, u32 v) {
  __hip_atomic_store(p, v, __ATOMIC_RELAXED, __HIP_MEMORY_SCOPE_AGENT);
}
__device__ __forceinline__ void ainc(u32* p) {
  __hip_atomic_fetch_add(p, 1u, __ATOMIC_RELAXED, __HIP_MEMORY_SCOPE_AGENT);
}

// --- zero the per-step counters --------------------------------------------
__global__ void clear_kernel(u32* __restrict__ cnt) {
  int i = blockIdx.x * 256 + threadIdx.x;
  if (i < NSTEP) cnt[i] = 0u;
}

// --- stim_applied[b][c] = sum_p stim[b][p] * spat[c][p] ---------------------
__global__ void applied_kernel(const float* __restrict__ stim,
                               const float* __restrict__ spat,
                               float* __restrict__ applied) {
  const int c = blockIdx.x, b = blockIdx.y;
  __shared__ float red[256];
  float a = 0.f;
  for (int p = threadIdx.x; p < NPIX; p += 256)
    a += stim[b * NPIX + p] * spat[c * NPIX + p];
  red[threadIdx.x] = a;
  __syncthreads();
  for (int s = 128; s > 0; s >>= 1) {
    if (threadIdx.x < s) red[threadIdx.x] += red[threadIdx.x + s];
    __syncthreads();
  }
  if (threadIdx.x == 0) applied[b * NC + c] = red[0];
}

// --- convT[t][c] = sum_f stc[t+f] * tcf[c][f] ------------------------------
__global__ void conv_kernel(const float* __restrict__ stc,
                            const float* __restrict__ tcf,
                            float* __restrict__ convT) {
  int idx = blockIdx.x * 256 + threadIdx.x;
  if (idx >= NSTEP * NC) return;
  int t = idx / NC, c = idx - t * NC;
  float a = 0.f;
  for (int f = 0; f < NBF; ++f)
    a += stc[t + f] * tcf[c * NBF + f];
  convT[idx] = a;
}

// --- packed, time-reversed, edge-paired filter table -----------------------
// wrevP[c][p][i]: pair p<10 -> (cf[c][2p][99-i], cf[c][2p+1][99-i]);
// p==10 -> (ff[c][99-i], 0).
__global__ void pack_kernel(const float* __restrict__ cf,
                            const float* __restrict__ ff,
                            u32* __restrict__ wrevP) {
  int idx = blockIdx.x * 256 + threadIdx.x;
  if (idx >= NC * 1100) return;
  int c = idx / 1100;
  int r = idx - c * 1100;
  int p = r / 100;
  int i = r - p * 100;
  int f = 99 - i;
  float lo, hi;
  if (p < 10) {
    lo = cf[(c * MC + 2 * p) * NBF + f];
    hi = cf[(c * MC + 2 * p + 1) * NBF + f];
  } else {
    lo = ff[c * NBF + f];
    hi = 0.f;
  }
  wrevP[idx] = pkrtz(lo, hi);
}

// --- packed source pairs selP[c][p] = src0 | (src1 << 16) ------------------
__global__ void selp_kernel(const int* __restrict__ sel, u32* __restrict__ selP) {
  int idx = blockIdx.x * 256 + threadIdx.x;
  if (idx >= NC * 10) return;
  int c = idx / 10, p = idx - c * 10;
  u32 s0 = (u32)sel[c * MC + 2 * p];
  u32 s1 = (u32)sel[c * MC + 2 * p + 1];
  selP[idx] = s0 | (s1 << 16);
}

// --- prefill ring[tau][c][b] = init[b][c][tau] for tau < 100 ---------------
__global__ void initT_kernel(const float* __restrict__ init,
                             float* __restrict__ ring) {
  int idx = blockIdx.x * 256 + threadIdx.x;
  if (idx >= NBI * NCB) return;
  int b = idx & (NBATCH - 1);
  int r = idx >> 5;          // c + NC*tau
  int c = r % NC;
  int tau = r / NC;
  ring[idx] = init[(b * NC + c) * NBI + tau];
}

// --- copy initial spikes into output (first 100 bins of each row) ----------
__global__ void copy_init_kernel(const float4* __restrict__ init,
                                 float4* __restrict__ out) {
  int idx = blockIdx.x * 256 + threadIdx.x;
  if (idx >= NBATCH * NC * (NBI / 4)) return;
  int k4 = idx % (NBI / 4);
  int bc = idx / (NBI / 4);
  out[bc * (NB / 4) + k4] = init[idx];
}

// --- the recurrence --------------------------------------------------------
__global__ __launch_bounds__(256) void sim_kernel(
    const float* __restrict__ bias, const float* __restrict__ applied,
    const float* __restrict__ convT, const u32* __restrict__ wrevP,
    const u32* __restrict__ selP, u32* __restrict__ ring,
    u32* __restrict__ cnt, float* __restrict__ out) {
  const int tid = threadIdx.x;
  const int b = tid & 31;
  const int ch = tid >> 5;
  const int c = blockIdx.x * CPW + ch;

  float acc[NBF];
#pragma unroll
  for (int i = 0; i < NBF; ++i) acc[i] = 0.f;

  u32 selp[10];
#pragma unroll
  for (int p = 0; p < 10; ++p) selp[p] = selP[c * 10 + p];

  const float biasv = bias[c];
  const float appv  = applied[b * NC + c];
  const u32* wb = wrevP + c * 1100;
  float* outS = out + (size_t)(b * NC + c) * NB + NBI;
  float* outG = out + (size_t)NBATCH * NC * NB + (size_t)(b * NC + c) * NSTEP;

#pragma unroll 1
  for (int tau = 0; tau < NB; ++tau) {
    const int t = tau - NBI;
    u32* rt = ring + (size_t)tau * NCB;
    float sv;
    if (t >= 0) {
      float g = biasv + appv * convT[t * NC + c] + acc[0];
      sv = 1.f / (1.f + __expf(-g));
      outS[t] = sv;
      outG[t] = g;
      astore(rt + c * NBATCH + b, __builtin_bit_cast(u32, sv));
      __syncthreads();  // drains vmcnt for ALL waves -> wg's stores visible
      if (tid == 0) ainc(&cnt[t]);
    } else {
      sv = __builtin_bit_cast(float, aload(rt + c * NBATCH + b));
    }

    // rotate: acc[i] <- contributions to step (t+1)+i
#pragma unroll
    for (int i = 0; i < NBF - 1; ++i) acc[i] = acc[i + 1];
    acc[NBF - 1] = 0.f;

    // feedback scatter (local data) — runs while the barrier settles
    {
      const u32 sp10 = pkrtz(sv, 0.f);
#pragma unroll
      for (int ib = 0; ib < 25; ++ib) {
        const uint4 w = *(const uint4*)(wb + 1000 + ib * 4);
        acc[ib * 4 + 0] = dot2(w.x, sp10, acc[ib * 4 + 0]);
        acc[ib * 4 + 1] = dot2(w.y, sp10, acc[ib * 4 + 1]);
        acc[ib * 4 + 2] = dot2(w.z, sp10, acc[ib * 4 + 2]);
        acc[ib * 4 + 3] = dot2(w.w, sp10, acc[ib * 4 + 3]);
      }
    }

    // barrier detect: ONLY wave 0 polls (with backoff); others wait at the
    // second __syncthreads. 75 pollers at ~1 req/µs each -> no MALL storm.
    if (t >= 0) {
      if (tid < 64) {
        while (aload(&cnt[t]) < NWG) { __builtin_amdgcn_s_sleep(1); }
      }
      __syncthreads();
    }

    u32 u0[10], u1[10];
#pragma unroll
    for (int p = 0; p < 10; ++p) {
      u0[p] = aload(rt + (selp[p] & 0xffffu) * NBATCH + b);
      u1[p] = aload(rt + (selp[p] >> 16) * NBATCH + b);
    }
    u32 sp[10];
#pragma unroll
    for (int p = 0; p < 10; ++p)
      sp[p] = pkrtz(__builtin_bit_cast(float, u0[p]),
                    __builtin_bit_cast(float, u1[p]));

    // coupling scatter: acc[i] += wrev[p][i] . sp[p]
#pragma unroll 1
    for (int p = 0; p < 10; ++p) {
#pragma unroll
      for (int ib = 0; ib < 25; ++ib) {
        const uint4 w = *(const uint4*)(wb + p * 100 + ib * 4);
        acc[ib * 4 + 0] = dot2(w.x, sp[p], acc[ib * 4 + 0]);
        acc[ib * 4 + 1] = dot2(w.y, sp[p], acc[ib * 4 + 1]);
        acc[ib * 4 + 2] = dot2(w.z, sp[p], acc[ib * 4 + 2]);
        acc[ib * 4 + 3] = dot2(w.w, sp[p], acc[ib * 4 + 3]);
      }
    }
  }
}

extern "C" void kernel_launch(void* const* d_in, const int* in_sizes, int n_in,
                              void* d_out, int out_size, void* d_ws, size_t ws_size,
                              hipStream_t stream) {
  const float* stim = (const float*)d_in[0];   // 32x64x64
  const float* init = (const float*)d_in[1];   // 32x600x100
  const float* spat = (const float*)d_in[2];   // 600x4096
  const float* tcf  = (const float*)d_in[3];   // 600x100
  const float* ff   = (const float*)d_in[4];   // 600x100
  const float* cf   = (const float*)d_in[5];   // 600x20x100
  const float* bias = (const float*)d_in[6];   // 600x1
  const int*   sel  = (const int*)d_in[7];     // 600x20 int32
  const float* stc  = (const float*)d_in[8];   // 500
  float* out = (float*)d_out;                  // spikes 32x600x500, gensig 32x600x400

  char* ws = (char*)d_ws;
  u32*   ring    = (u32*)ws;                         // 38,400,000 B (500x600x32 f32)
  float* applied = (float*)(ws + 38400000);          //     76,800 B
  float* convT   = (float*)(ws + 38476800);          //    960,000 B
  u32*   wrevP   = (u32*)(ws + 39436800);            //  2,640,000 B
  u32*   selP    = (u32*)(ws + 42076800);            //     24,000 B
  u32*   cnt     = (u32*)(ws + 42100800);            //      1,600 B  (end ~42.1 MB)
  (void)ws_size; (void)in_sizes; (void)n_in; (void)out_size;

  hipLaunchKernelGGL(clear_kernel, dim3((NSTEP + 255) / 256), dim3(256), 0,
                     stream, cnt);
  hipLaunchKernelGGL(applied_kernel, dim3(NC, NBATCH), dim3(256), 0, stream,
                     stim, spat, applied);
  hipLaunchKernelGGL(conv_kernel, dim3((NSTEP * NC + 255) / 256), dim3(256), 0,
                     stream, stc, tcf, convT);
  hipLaunchKernelGGL(pack_kernel, dim3((NC * 1100 + 255) / 256), dim3(256), 0,
                     stream, cf, ff, wrevP);
  hipLaunchKernelGGL(selp_kernel, dim3((NC * 10 + 255) / 256), dim3(256), 0,
                     stream, sel, selP);
  hipLaunchKernelGGL(initT_kernel, dim3((NBI * NCB + 255) / 256), dim3(256), 0,
                     stream, init, (float*)ring);
  hipLaunchKernelGGL(copy_init_kernel,
                     dim3((NBATCH * NC * (NBI / 4) + 255) / 256), dim3(256), 0,
                     stream, (const float4*)init, (float4*)out);
  hipLaunchKernelGGL(sim_kernel, dim3(NWG), dim3(256), 0, stream,
                     bias, applied, convT, wrevP, selP, ring, cnt, out);
}